// Round 2
// baseline (556.815 us; speedup 1.0000x reference)
//
#include <hip/hip_runtime.h>

typedef __bf16 bf16_t;
typedef __bf16 bf16x8 __attribute__((ext_vector_type(8)));
typedef float f32x4 __attribute__((ext_vector_type(4)));

#define NL 3
#define HD 128
#define ROWS 64
#define STR 136          // bf16 row stride for S/SR tiles (272 B = 16*17 -> 16B-aligned, 2-way LDS aliasing = free)
#define THREADS 512
#define BATCH 262144
#define NBLK (BATCH / ROWS)

// ws (d_ws) layout in bf16 elements: weights pre-swizzled into MFMA B-fragment order
#define SW_OFF 0                 // [ct=8][lane=64][j=8]                       = 4096
#define U_OFF  4096              // [l=3][g=4][ct=8][lane=64][j=8]             = 49152
#define W_OFF  53248             // [l=3][g=4][ct=8][kc=4][lane=64][j=8]       = 196608
#define WS_ELEMS 249856          // total bf16 elems (499712 bytes)

#define MFMA(a, b, c) __builtin_amdgcn_mfma_f32_16x16x32_bf16((a), (b), (c), 0, 0, 0)

__device__ __forceinline__ float sigm(float v) { return 1.f / (1.f + __expf(-v)); }
__device__ __forceinline__ float tanh_f(float v) { return 1.f - 2.f / (__expf(2.f * v) + 1.f); }

// ---------------- prep: swizzle f32 weights into bf16 MFMA B-fragment order in ws ----------------
// B-frag layout for mfma_f32_16x16x32_bf16: lane holds B[k = (lane>>4)*8 + j][n = lane&15]
__global__ void dgm_prep(const float* __restrict__ SwW,
                         const float* __restrict__ Uz, const float* __restrict__ Wz,
                         const float* __restrict__ Ug, const float* __restrict__ Wg,
                         const float* __restrict__ Ur, const float* __restrict__ Wr,
                         const float* __restrict__ Uh, const float* __restrict__ Wh,
                         bf16_t* __restrict__ ws) {
    int idx = blockIdx.x * 256 + threadIdx.x;
    if (idx >= WS_ELEMS) return;
    const float* Us[4] = {Uz, Ug, Ur, Uh};
    const float* Wm[4] = {Wz, Wg, Wr, Wh};
    if (idx < U_OFF) {
        int ct = idx >> 9, rem = idx & 511, lane = rem >> 3, j = rem & 7;
        int q = lane >> 4, mm = lane & 15;
        int k = q * 8 + j, n = ct * 16 + mm;
        ws[idx] = (k < 8) ? (bf16_t)SwW[k * HD + n] : (bf16_t)0.f;
    } else if (idx < W_OFF) {
        int t = idx - U_OFF;
        int lg = t >> 12, r2 = t & 4095;
        int l = lg >> 2, g = lg & 3;
        int ct = r2 >> 9, rem = r2 & 511, lane = rem >> 3, j = rem & 7;
        int q = lane >> 4, mm = lane & 15;
        int k = q * 8 + j, n = ct * 16 + mm;
        ws[idx] = (k < 8) ? (bf16_t)Us[g][(l * 8 + k) * HD + n] : (bf16_t)0.f;
    } else {
        int t = idx - W_OFF;
        int lg = t >> 14, r2 = t & 16383;
        int l = lg >> 2, g = lg & 3;
        int ct = r2 >> 11, kc = (r2 >> 9) & 3, rem = r2 & 511, lane = rem >> 3, j = rem & 7;
        int q = lane >> 4, mm = lane & 15;
        int k = kc * 32 + q * 8 + j, n = ct * 16 + mm;
        ws[idx] = (bf16_t)Wm[g][(l * HD + k) * HD + n];
    }
}

// ---------------- main fused kernel ----------------
__device__ __forceinline__ void stage1(const bf16_t* __restrict__ src, bf16_t* dst, int tid) {
    const uint4* s = (const uint4*)src;
    uint4* d = (uint4*)dst;
#pragma unroll
    for (int i = 0; i < 4; i++) d[tid + i * THREADS] = s[tid + i * THREADS];
}

__device__ __forceinline__ void stage3(const bf16_t* __restrict__ ws, int l,
                                       bf16_t (*wst)[8 * 4 * 64 * 8], int tid) {
    // slot0 <- Wr, slot1 <- Wz, slot2 <- Wg
    stage1(ws + W_OFF + (size_t)(l * 4 + 2) * 16384, wst[0], tid);
    stage1(ws + W_OFF + (size_t)(l * 4 + 0) * 16384, wst[1], tid);
    stage1(ws + W_OFF + (size_t)(l * 4 + 1) * 16384, wst[2], tid);
}

__global__ __launch_bounds__(THREADS) void dgm_main(
    const float* __restrict__ x,
    const float* __restrict__ Swb,
    const float* __restrict__ Bz, const float* __restrict__ Bg,
    const float* __restrict__ Br, const float* __restrict__ Bh,
    const float* __restrict__ WfW, const float* __restrict__ WfB,
    const bf16_t* __restrict__ ws,
    float* __restrict__ out) {
    __shared__ __align__(16) bf16_t s_sig[2][ROWS * STR];  // sigma(S) ping-pong
    __shared__ __align__(16) bf16_t s_r[ROWS * STR];       // sigma(S)*R
    __shared__ __align__(16) bf16_t wst[3][8 * 4 * 64 * 8];
    // final raw S3 in f32, aliasing wst[1] (dead after last P2): 64*128 floats = 32768 B
    float* fS = (float*)(&wst[1][0]);

    const int tid = threadIdx.x;
    const int lane = tid & 63;
    const int wv = tid >> 6;           // 0..7
    const int rt = wv >> 1;            // row-tile 0..3 (16 rows each)
    const int ch = wv & 1;             // col half: ctiles ch*4 .. ch*4+3
    const int m = lane & 15, q = lane >> 4;
    const int rb = blockIdx.x * ROWS;

    // x A-fragment: lanes with q==0 hold x[row][0..7] (f32 -> bf16); quads 1..3 are K-padding zeros
    bf16x8 xf;
#pragma unroll
    for (int i = 0; i < 8; i++) xf[i] = (bf16_t)0.f;
    if (q == 0) {
        const float* xr = x + (size_t)(rb + rt * 16 + m) * 8;
#pragma unroll
        for (int i = 0; i < 8; i++) xf[i] = (bf16_t)xr[i];
    }

    // ---- init: S0 = x@Sw + b ; store sigma(S0) (layer 0 consumes sigmoided S)
#pragma unroll
    for (int ci = 0; ci < 4; ci++) {
        int ct = ch * 4 + ci;
        bf16x8 bu = *(const bf16x8*)(ws + SW_OFF + (ct * 64 + lane) * 8);
        f32x4 acc = {0.f, 0.f, 0.f, 0.f};
        acc = MFMA(xf, bu, acc);
        float bb = Swb[ct * 16 + m];
#pragma unroll
        for (int i = 0; i < 4; i++) {
            int r = rt * 16 + q * 4 + i, c = ct * 16 + m;
            s_sig[0][r * STR + c] = (bf16_t)sigm(acc[i] + bb);
        }
    }
    stage3(ws, 0, wst, tid);
    __syncthreads();

    f32x4 accZ[4], accG[4];
    for (int l = 0; l < NL; l++) {
        const int cur = l & 1;
        const int nxt = cur ^ 1;
        const bf16_t* uf = ws + U_OFF + (size_t)l * 4 * 4096;

        // ---- P1: R = sigm(x@Ur + Ssig@Wr + br);  SR = Ssig*R
#pragma unroll
        for (int ci = 0; ci < 4; ci++) {
            int ct = ch * 4 + ci;
            bf16x8 bu = *(const bf16x8*)(uf + 2 * 4096 + (ct * 64 + lane) * 8);
            f32x4 acc = {0.f, 0.f, 0.f, 0.f};
            acc = MFMA(xf, bu, acc);
#pragma unroll
            for (int kc = 0; kc < 4; kc++) {
                bf16x8 a = *(const bf16x8*)(&s_sig[cur][(rt * 16 + m) * STR + kc * 32 + q * 8]);
                bf16x8 b = *(const bf16x8*)(&wst[0][((ct * 4 + kc) * 64 + lane) * 8]);
                acc = MFMA(a, b, acc);
            }
            float bb = Br[l * HD + ct * 16 + m];
#pragma unroll
            for (int i = 0; i < 4; i++) {
                int r = rt * 16 + q * 4 + i, c = ct * 16 + m;
                float rv = sigm(acc[i] + bb);
                float sv = (float)s_sig[cur][r * STR + c];
                s_r[r * STR + c] = (bf16_t)(rv * sv);
            }
        }
        __syncthreads();

        // ---- P2: stage Wh into slot0 (Wr dead); Z and G MFMAs, accs held in regs
        stage1(ws + W_OFF + (size_t)(l * 4 + 3) * 16384, wst[0], tid);
#pragma unroll
        for (int ci = 0; ci < 4; ci++) {
            int ct = ch * 4 + ci;
            bf16x8 buz = *(const bf16x8*)(uf + 0 * 4096 + (ct * 64 + lane) * 8);
            bf16x8 bug = *(const bf16x8*)(uf + 1 * 4096 + (ct * 64 + lane) * 8);
            f32x4 az = {0.f, 0.f, 0.f, 0.f}, ag = {0.f, 0.f, 0.f, 0.f};
            az = MFMA(xf, buz, az);
            ag = MFMA(xf, bug, ag);
#pragma unroll
            for (int kc = 0; kc < 4; kc++) {
                bf16x8 a = *(const bf16x8*)(&s_sig[cur][(rt * 16 + m) * STR + kc * 32 + q * 8]);
                bf16x8 bz_ = *(const bf16x8*)(&wst[1][((ct * 4 + kc) * 64 + lane) * 8]);
                bf16x8 bg_ = *(const bf16x8*)(&wst[2][((ct * 4 + kc) * 64 + lane) * 8]);
                az = MFMA(a, bz_, az);
                ag = MFMA(a, bg_, ag);
            }
            accZ[ci] = az;
            accG[ci] = ag;
        }
        __syncthreads();

        // ---- P3: H from SR; combine; write sigma(Snew) (raw f32 Snew into fS on last layer)
#pragma unroll
        for (int ci = 0; ci < 4; ci++) {
            int ct = ch * 4 + ci;
            bf16x8 buh = *(const bf16x8*)(uf + 3 * 4096 + (ct * 64 + lane) * 8);
            f32x4 ah = {0.f, 0.f, 0.f, 0.f};
            ah = MFMA(xf, buh, ah);
#pragma unroll
            for (int kc = 0; kc < 4; kc++) {
                bf16x8 a = *(const bf16x8*)(&s_r[(rt * 16 + m) * STR + kc * 32 + q * 8]);
                bf16x8 b = *(const bf16x8*)(&wst[0][((ct * 4 + kc) * 64 + lane) * 8]);
                ah = MFMA(a, b, ah);
            }
            float bz = Bz[l * HD + ct * 16 + m];
            float bg = Bg[l * HD + ct * 16 + m];
            float bh = Bh[l * HD + ct * 16 + m];
#pragma unroll
            for (int i = 0; i < 4; i++) {
                int r = rt * 16 + q * 4 + i, c = ct * 16 + m;
                float z = sigm(accZ[ci][i] + bz);
                float g = sigm(accG[ci][i] + bg);
                float hh = tanh_f(ah[i] + bh);
                float sv = (float)s_sig[cur][r * STR + c];
                float sn = (1.f - g) * hh + z * sv;
                if (l == NL - 1) fS[r * HD + c] = sn;            // raw S3, f32 (aliases dead wst[1])
                else s_sig[nxt][r * STR + c] = (bf16_t)sigm(sn);
            }
        }
        __syncthreads();
        if (l < NL - 1) {
            stage3(ws, l + 1, wst, tid);
            __syncthreads();
        }
    }

    // ---- final: out = S3 @ Wf + bf   (f32 S3 from fS)
    {
        int r = tid >> 3, s = tid & 7;
        const float* row = &fS[r * HD];
        float p = 0.f;
#pragma unroll
        for (int j = 0; j < 16; j++) p += row[s * 16 + j] * WfW[s * 16 + j];
        p += __shfl_xor(p, 1, 8);
        p += __shfl_xor(p, 2, 8);
        p += __shfl_xor(p, 4, 8);
        if (s == 0) out[rb + r] = p + WfB[0];
    }
}

extern "C" void kernel_launch(void* const* d_in, const int* in_sizes, int n_in,
                              void* d_out, int out_size, void* d_ws, size_t ws_size,
                              hipStream_t stream) {
    const float* x   = (const float*)d_in[0];
    const float* SwW = (const float*)d_in[1];
    const float* Swb = (const float*)d_in[2];
    const float* Uz  = (const float*)d_in[3];
    const float* Wz  = (const float*)d_in[4];
    const float* Bz  = (const float*)d_in[5];
    const float* Ug  = (const float*)d_in[6];
    const float* Wg  = (const float*)d_in[7];
    const float* Bg  = (const float*)d_in[8];
    const float* Ur  = (const float*)d_in[9];
    const float* Wr  = (const float*)d_in[10];
    const float* Br  = (const float*)d_in[11];
    const float* Uh  = (const float*)d_in[12];
    const float* Wh  = (const float*)d_in[13];
    const float* Bh  = (const float*)d_in[14];
    const float* WfW = (const float*)d_in[15];
    const float* WfB = (const float*)d_in[16];
    bf16_t* ws = (bf16_t*)d_ws;
    float* out = (float*)d_out;

    if (ws_size < (size_t)WS_ELEMS * sizeof(bf16_t)) return;  // need ~500 KB scratch

    dgm_prep<<<(WS_ELEMS + 255) / 256, 256, 0, stream>>>(SwW, Uz, Wz, Ug, Wg, Ur, Wr, Uh, Wh, ws);
    dgm_main<<<NBLK, THREADS, 0, stream>>>(x, Swb, Bz, Bg, Br, Bh, WfW, WfB, ws, out);
}

// Round 3
// 499.855 us; speedup vs baseline: 1.1140x; 1.1140x over previous
//
#include <hip/hip_runtime.h>

typedef __bf16 bf16_t;
typedef __bf16 bf16x8 __attribute__((ext_vector_type(8)));
typedef float f32x4 __attribute__((ext_vector_type(4)));

#define NL 3
#define HD 128
#define ROWS 64
#define STR 136          // bf16 row stride for S/SR tiles (272 B -> 16B-aligned, ~2-way LDS aliasing = free)
#define THREADS 512
#define BATCH 262144
#define NBLK (BATCH / ROWS)

// ws (d_ws) layout in bf16 elements: weights pre-swizzled into MFMA B-fragment order
#define SW_OFF 0                 // [ct=8][lane=64][j=8]                       = 4096
#define U_OFF  4096              // [l=3][g=4][ct=8][lane=64][j=8]             = 49152
#define W_OFF  53248             // [l=3][g=4][ct=8][kc=4][lane=64][j=8]       = 196608
#define WS_ELEMS 249856          // total bf16 elems (499712 bytes)

#define MFMA(a, b, c) __builtin_amdgcn_mfma_f32_16x16x32_bf16((a), (b), (c), 0, 0, 0)

__device__ __forceinline__ float sigm(float v) { return 1.f / (1.f + __expf(-v)); }
__device__ __forceinline__ float tanh_f(float v) { return 1.f - 2.f / (__expf(2.f * v) + 1.f); }

// ---------------- prep: swizzle f32 weights into bf16 MFMA B-fragment order in ws ----------------
// B-frag layout for mfma_f32_16x16x32_bf16: lane holds B[k = (lane>>4)*8 + j][n = lane&15]
__global__ void dgm_prep(const float* __restrict__ SwW,
                         const float* __restrict__ Uz, const float* __restrict__ Wz,
                         const float* __restrict__ Ug, const float* __restrict__ Wg,
                         const float* __restrict__ Ur, const float* __restrict__ Wr,
                         const float* __restrict__ Uh, const float* __restrict__ Wh,
                         bf16_t* __restrict__ ws) {
    int idx = blockIdx.x * 256 + threadIdx.x;
    if (idx >= WS_ELEMS) return;
    const float* Us[4] = {Uz, Ug, Ur, Uh};
    const float* Wm[4] = {Wz, Wg, Wr, Wh};
    if (idx < U_OFF) {
        int ct = idx >> 9, rem = idx & 511, lane = rem >> 3, j = rem & 7;
        int q = lane >> 4, mm = lane & 15;
        int k = q * 8 + j, n = ct * 16 + mm;
        ws[idx] = (k < 8) ? (bf16_t)SwW[k * HD + n] : (bf16_t)0.f;
    } else if (idx < W_OFF) {
        int t = idx - U_OFF;
        int lg = t >> 12, r2 = t & 4095;
        int l = lg >> 2, g = lg & 3;
        int ct = r2 >> 9, rem = r2 & 511, lane = rem >> 3, j = rem & 7;
        int q = lane >> 4, mm = lane & 15;
        int k = q * 8 + j, n = ct * 16 + mm;
        ws[idx] = (k < 8) ? (bf16_t)Us[g][(l * 8 + k) * HD + n] : (bf16_t)0.f;
    } else {
        int t = idx - W_OFF;
        int lg = t >> 14, r2 = t & 16383;
        int l = lg >> 2, g = lg & 3;
        int ct = r2 >> 11, kc = (r2 >> 9) & 3, rem = r2 & 511, lane = rem >> 3, j = rem & 7;
        int q = lane >> 4, mm = lane & 15;
        int k = kc * 32 + q * 8 + j, n = ct * 16 + mm;
        ws[idx] = (bf16_t)Wm[g][(l * HD + k) * HD + n];
    }
}

// ---------------- main fused kernel: wave = one 16-col tile, weights in registers ----------------
__global__ __launch_bounds__(THREADS, 2) void dgm_main(
    const float* __restrict__ x,
    const float* __restrict__ Swb,
    const float* __restrict__ Bz, const float* __restrict__ Bg,
    const float* __restrict__ Br, const float* __restrict__ Bh,
    const float* __restrict__ WfW, const float* __restrict__ WfB,
    const bf16_t* __restrict__ ws,
    float* __restrict__ out) {
    __shared__ __align__(16) bf16_t s_sig[ROWS * STR];  // sigma(S), updated in place (owner-thread elems)
    __shared__ __align__(16) bf16_t s_r[ROWS * STR];    // sigma(S)*R
    __shared__ float red[ROWS];                          // final-dot reduction

    const int tid = threadIdx.x;
    const int lane = tid & 63;
    const int ct = tid >> 6;           // wave owns column tile ct (cols ct*16..ct*16+15), all 64 rows
    const int m = lane & 15, q = lane >> 4;
    const int rb = blockIdx.x * ROWS;
    const int c = ct * 16 + m;         // this thread's fixed output column

    if (tid < ROWS) red[tid] = 0.f;

    // x A-fragments for the 4 row-tiles (lanes q==0 hold x[row][0..7]; quads 1..3 zero K-padding)
    bf16x8 xf[4];
#pragma unroll
    for (int rt = 0; rt < 4; rt++) {
#pragma unroll
        for (int i = 0; i < 8; i++) xf[rt][i] = (bf16_t)0.f;
        if (q == 0) {
            const float* xr = x + (size_t)(rb + rt * 16 + m) * 8;
#pragma unroll
            for (int i = 0; i < 8; i++) xf[rt][i] = (bf16_t)xr[i];
        }
    }

    const float swb = Swb[c];
    const float wfc = WfW[c];

    // ---- init: S0 = x@Sw + b; sv = sigma(S0) in regs + LDS
    float sv[4][4];
    {
        bf16x8 fSw = *(const bf16x8*)(ws + SW_OFF + (ct * 64 + lane) * 8);
#pragma unroll
        for (int rt = 0; rt < 4; rt++) {
            f32x4 acc = {0.f, 0.f, 0.f, 0.f};
            acc = MFMA(xf[rt], fSw, acc);
#pragma unroll
            for (int i = 0; i < 4; i++) {
                float s0 = sigm(acc[i] + swb);
                sv[rt][i] = s0;
                s_sig[(rt * 16 + q * 4 + i) * STR + c] = (bf16_t)s0;
            }
        }
    }
    __syncthreads();

    f32x4 accZ[4], accG[4];
#pragma unroll 1
    for (int l = 0; l < NL; l++) {
        const bf16_t* wb = ws + W_OFF + (size_t)l * 4 * 16384;
        const bf16_t* ub = ws + U_OFF + (size_t)l * 4 * 4096;

        // this wave's weight fragments for the whole layer, straight from L2 into registers
        bf16x8 fU[4], fW[4][4];
#pragma unroll
        for (int g = 0; g < 4; g++) {
            fU[g] = *(const bf16x8*)(ub + g * 4096 + (ct * 64 + lane) * 8);
#pragma unroll
            for (int kc = 0; kc < 4; kc++)
                fW[g][kc] = *(const bf16x8*)(wb + g * 16384 + ((ct * 4 + kc) * 64 + lane) * 8);
        }
        const float bz = Bz[l * HD + c], bg = Bg[l * HD + c];
        const float br = Br[l * HD + c], bh = Bh[l * HD + c];

        // ---- P_A: Z, G, R share each sigma(S) A-fragment; epilogue writes SR
#pragma unroll
        for (int rt = 0; rt < 4; rt++) {
            f32x4 aZ = {0.f, 0.f, 0.f, 0.f}, aG = {0.f, 0.f, 0.f, 0.f}, aR = {0.f, 0.f, 0.f, 0.f};
            aZ = MFMA(xf[rt], fU[0], aZ);
            aG = MFMA(xf[rt], fU[1], aG);
            aR = MFMA(xf[rt], fU[2], aR);
#pragma unroll
            for (int kc = 0; kc < 4; kc++) {
                bf16x8 a = *(const bf16x8*)(&s_sig[(rt * 16 + m) * STR + kc * 32 + q * 8]);
                aZ = MFMA(a, fW[0][kc], aZ);
                aG = MFMA(a, fW[1][kc], aG);
                aR = MFMA(a, fW[2][kc], aR);
            }
            accZ[rt] = aZ;
            accG[rt] = aG;
#pragma unroll
            for (int i = 0; i < 4; i++) {
                float rv = sigm(aR[i] + br);
                s_r[(rt * 16 + q * 4 + i) * STR + c] = (bf16_t)(rv * sv[rt][i]);
            }
        }
        __syncthreads();

        // ---- P_B: H from SR; combine; in-place sigma(S_next) (or final-dot partials on last layer)
        const bool last = (l == NL - 1);
#pragma unroll
        for (int rt = 0; rt < 4; rt++) {
            f32x4 aH = {0.f, 0.f, 0.f, 0.f};
            aH = MFMA(xf[rt], fU[3], aH);
#pragma unroll
            for (int kc = 0; kc < 4; kc++) {
                bf16x8 a = *(const bf16x8*)(&s_r[(rt * 16 + m) * STR + kc * 32 + q * 8]);
                aH = MFMA(a, fW[3][kc], aH);
            }
#pragma unroll
            for (int i = 0; i < 4; i++) {
                float z = sigm(accZ[rt][i] + bz);
                float g = sigm(accG[rt][i] + bg);
                float hh = tanh_f(aH[i] + bh);
                float sn = (1.f - g) * hh + z * sv[rt][i];
                if (last) {
                    float p = sn * wfc;           // S3 stays f32: fold S3@Wf into epilogue
                    p += __shfl_xor(p, 1);
                    p += __shfl_xor(p, 2);
                    p += __shfl_xor(p, 4);
                    p += __shfl_xor(p, 8);
                    if (m == 0) atomicAdd(&red[rt * 16 + q * 4 + i], p);
                } else {
                    float s2 = sigm(sn);
                    sv[rt][i] = s2;
                    s_sig[(rt * 16 + q * 4 + i) * STR + c] = (bf16_t)s2;  // own elem: race-free in place
                }
            }
        }
        __syncthreads();
    }

    if (tid < ROWS) out[rb + tid] = red[tid] + WfB[0];
}

extern "C" void kernel_launch(void* const* d_in, const int* in_sizes, int n_in,
                              void* d_out, int out_size, void* d_ws, size_t ws_size,
                              hipStream_t stream) {
    const float* x   = (const float*)d_in[0];
    const float* SwW = (const float*)d_in[1];
    const float* Swb = (const float*)d_in[2];
    const float* Uz  = (const float*)d_in[3];
    const float* Wz  = (const float*)d_in[4];
    const float* Bz  = (const float*)d_in[5];
    const float* Ug  = (const float*)d_in[6];
    const float* Wg  = (const float*)d_in[7];
    const float* Bg  = (const float*)d_in[8];
    const float* Ur  = (const float*)d_in[9];
    const float* Wr  = (const float*)d_in[10];
    const float* Br  = (const float*)d_in[11];
    const float* Uh  = (const float*)d_in[12];
    const float* Wh  = (const float*)d_in[13];
    const float* Bh  = (const float*)d_in[14];
    const float* WfW = (const float*)d_in[15];
    const float* WfB = (const float*)d_in[16];
    bf16_t* ws = (bf16_t*)d_ws;
    float* out = (float*)d_out;

    if (ws_size < (size_t)WS_ELEMS * sizeof(bf16_t)) return;  // need ~500 KB scratch

    dgm_prep<<<(WS_ELEMS + 255) / 256, 256, 0, stream>>>(SwW, Uz, Wz, Ug, Wg, Ur, Wr, Uh, Wh, ws);
    dgm_main<<<NBLK, THREADS, 0, stream>>>(x, Swb, Bz, Bg, Br, Bh, WfW, WfB, ws, out);
}

// Round 4
// 381.796 us; speedup vs baseline: 1.4584x; 1.3092x over previous
//
#include <hip/hip_runtime.h>

typedef __bf16 bf16_t;
typedef __bf16 bf16x8 __attribute__((ext_vector_type(8)));
typedef float f32x4 __attribute__((ext_vector_type(4)));

#define NL 3
#define HD 128
#define ROWS 64
#define STR 136          // bf16 row stride for S/SR tiles (272 B -> 16B-aligned, ~2-way LDS aliasing = free)
#define THREADS 512
#define BATCH 262144
#define NBLK (BATCH / ROWS)

// ws (d_ws) layout in bf16 elements: weights pre-swizzled into MFMA B-fragment order
#define SW_OFF 0                 // [ct=8][lane=64][j=8]                       = 4096
#define U_OFF  4096              // [l=3][g=4][ct=8][lane=64][j=8]             = 49152
#define W_OFF  53248             // [l=3][g=4][ct=8][kc=4][lane=64][j=8]       = 196608
#define WS_ELEMS 249856          // total bf16 elems (499712 bytes)

#define MFMA(a, b, c) __builtin_amdgcn_mfma_f32_16x16x32_bf16((a), (b), (c), 0, 0, 0)

// 4-VALU activations: v_exp_f32 + v_rcp_f32 (1-ulp, saturating limits are exact)
#define LOG2E 1.4426950408889634f
__device__ __forceinline__ float sigm(float v) {
    return __builtin_amdgcn_rcpf(1.f + __builtin_amdgcn_exp2f(-LOG2E * v));
}
__device__ __forceinline__ float tanh_f(float v) {
    return 1.f - 2.f * __builtin_amdgcn_rcpf(__builtin_amdgcn_exp2f((2.f * LOG2E) * v) + 1.f);
}

// ---------------- prep: swizzle f32 weights into bf16 MFMA B-fragment order in ws ----------------
// B-frag layout for mfma_f32_16x16x32_bf16: lane holds B[k = (lane>>4)*8 + j][n = lane&15]
__global__ void dgm_prep(const float* __restrict__ SwW,
                         const float* __restrict__ Uz, const float* __restrict__ Wz,
                         const float* __restrict__ Ug, const float* __restrict__ Wg,
                         const float* __restrict__ Ur, const float* __restrict__ Wr,
                         const float* __restrict__ Uh, const float* __restrict__ Wh,
                         bf16_t* __restrict__ ws) {
    int idx = blockIdx.x * 256 + threadIdx.x;
    if (idx >= WS_ELEMS) return;
    const float* Us[4] = {Uz, Ug, Ur, Uh};
    const float* Wm[4] = {Wz, Wg, Wr, Wh};
    if (idx < U_OFF) {
        int ct = idx >> 9, rem = idx & 511, lane = rem >> 3, j = rem & 7;
        int q = lane >> 4, mm = lane & 15;
        int k = q * 8 + j, n = ct * 16 + mm;
        ws[idx] = (k < 8) ? (bf16_t)SwW[k * HD + n] : (bf16_t)0.f;
    } else if (idx < W_OFF) {
        int t = idx - U_OFF;
        int lg = t >> 12, r2 = t & 4095;
        int l = lg >> 2, g = lg & 3;
        int ct = r2 >> 9, rem = r2 & 511, lane = rem >> 3, j = rem & 7;
        int q = lane >> 4, mm = lane & 15;
        int k = q * 8 + j, n = ct * 16 + mm;
        ws[idx] = (k < 8) ? (bf16_t)Us[g][(l * 8 + k) * HD + n] : (bf16_t)0.f;
    } else {
        int t = idx - W_OFF;
        int lg = t >> 14, r2 = t & 16383;
        int l = lg >> 2, g = lg & 3;
        int ct = r2 >> 11, kc = (r2 >> 9) & 3, rem = r2 & 511, lane = rem >> 3, j = rem & 7;
        int q = lane >> 4, mm = lane & 15;
        int k = kc * 32 + q * 8 + j, n = ct * 16 + mm;
        ws[idx] = (bf16_t)Wm[g][(l * HD + k) * HD + n];
    }
}

// ---------------- main fused kernel: wave = one 16-col tile, weights in registers ----------------
__global__ __launch_bounds__(THREADS) void dgm_main(
    const float* __restrict__ x,
    const float* __restrict__ Swb,
    const float* __restrict__ Bz, const float* __restrict__ Bg,
    const float* __restrict__ Br, const float* __restrict__ Bh,
    const float* __restrict__ WfW, const float* __restrict__ WfB,
    const bf16_t* __restrict__ ws,
    float* __restrict__ out) {
    __shared__ __align__(16) bf16_t s_sig[ROWS * STR];  // sigma(S), updated in place (owner-thread elems)
    __shared__ __align__(16) bf16_t s_r[ROWS * STR];    // sigma(S)*R
    __shared__ float red[ROWS];                          // final-dot reduction

    const int tid = threadIdx.x;
    const int lane = tid & 63;
    const int ct = tid >> 6;           // wave owns column tile ct (cols ct*16..ct*16+15), all 64 rows
    const int m = lane & 15, q = lane >> 4;
    const int rb = blockIdx.x * ROWS;
    const int c = ct * 16 + m;         // this thread's fixed output column

    if (tid < ROWS) red[tid] = 0.f;

    // x A-fragments for the 4 row-tiles (lanes q==0 hold x[row][0..7]; quads 1..3 zero K-padding)
    bf16x8 xf[4];
#pragma unroll
    for (int rt = 0; rt < 4; rt++) {
#pragma unroll
        for (int i = 0; i < 8; i++) xf[rt][i] = (bf16_t)0.f;
        if (q == 0) {
            const float* xr = x + (size_t)(rb + rt * 16 + m) * 8;
#pragma unroll
            for (int i = 0; i < 8; i++) xf[rt][i] = (bf16_t)xr[i];
        }
    }

    const float swb = Swb[c];
    const float wfc = WfW[c];

    // ---- init: S0 = x@Sw + b; sv = sigma(S0) in regs + LDS
    float sv[4][4];
    {
        bf16x8 fSw = *(const bf16x8*)(ws + SW_OFF + (ct * 64 + lane) * 8);
#pragma unroll
        for (int rt = 0; rt < 4; rt++) {
            f32x4 acc = {0.f, 0.f, 0.f, 0.f};
            acc = MFMA(xf[rt], fSw, acc);
#pragma unroll
            for (int i = 0; i < 4; i++) {
                float s0 = sigm(acc[i] + swb);
                sv[rt][i] = s0;
                s_sig[(rt * 16 + q * 4 + i) * STR + c] = (bf16_t)s0;
            }
        }
    }
    __syncthreads();

    f32x4 accZ[4], accG[4];
#pragma unroll 1
    for (int l = 0; l < NL; l++) {
        const bf16_t* wb = ws + W_OFF + (size_t)l * 4 * 16384;
        const bf16_t* ub = ws + U_OFF + (size_t)l * 4 * 4096;

        // this wave's weight fragments for the whole layer, straight from L2 into registers
        bf16x8 fU[4], fW[4][4];
#pragma unroll
        for (int g = 0; g < 4; g++) {
            fU[g] = *(const bf16x8*)(ub + g * 4096 + (ct * 64 + lane) * 8);
#pragma unroll
            for (int kc = 0; kc < 4; kc++)
                fW[g][kc] = *(const bf16x8*)(wb + g * 16384 + ((ct * 4 + kc) * 64 + lane) * 8);
        }
        const float bz = Bz[l * HD + c], bg = Bg[l * HD + c];
        const float br = Br[l * HD + c], bh = Bh[l * HD + c];

        // ---- P_A: Z, G, R share each sigma(S) A-fragment; epilogue writes SR
#pragma unroll
        for (int rt = 0; rt < 4; rt++) {
            f32x4 aZ = {0.f, 0.f, 0.f, 0.f}, aG = {0.f, 0.f, 0.f, 0.f}, aR = {0.f, 0.f, 0.f, 0.f};
            aZ = MFMA(xf[rt], fU[0], aZ);
            aG = MFMA(xf[rt], fU[1], aG);
            aR = MFMA(xf[rt], fU[2], aR);
#pragma unroll
            for (int kc = 0; kc < 4; kc++) {
                bf16x8 a = *(const bf16x8*)(&s_sig[(rt * 16 + m) * STR + kc * 32 + q * 8]);
                aZ = MFMA(a, fW[0][kc], aZ);
                aG = MFMA(a, fW[1][kc], aG);
                aR = MFMA(a, fW[2][kc], aR);
            }
            accZ[rt] = aZ;
            accG[rt] = aG;
#pragma unroll
            for (int i = 0; i < 4; i++) {
                float rv = sigm(aR[i] + br);
                s_r[(rt * 16 + q * 4 + i) * STR + c] = (bf16_t)(rv * sv[rt][i]);
            }
        }
        __syncthreads();

        // ---- P_B: H from SR; combine; in-place sigma(S_next) (or final-dot partials on last layer)
        const bool last = (l == NL - 1);
#pragma unroll
        for (int rt = 0; rt < 4; rt++) {
            f32x4 aH = {0.f, 0.f, 0.f, 0.f};
            aH = MFMA(xf[rt], fU[3], aH);
#pragma unroll
            for (int kc = 0; kc < 4; kc++) {
                bf16x8 a = *(const bf16x8*)(&s_r[(rt * 16 + m) * STR + kc * 32 + q * 8]);
                aH = MFMA(a, fW[3][kc], aH);
            }
#pragma unroll
            for (int i = 0; i < 4; i++) {
                float z = sigm(accZ[rt][i] + bz);
                float g = sigm(accG[rt][i] + bg);
                float hh = tanh_f(aH[i] + bh);
                float sn = (1.f - g) * hh + z * sv[rt][i];
                if (last) {
                    float p = sn * wfc;           // S3 stays f32: fold S3@Wf into epilogue
                    p += __shfl_xor(p, 1);
                    p += __shfl_xor(p, 2);
                    p += __shfl_xor(p, 4);
                    p += __shfl_xor(p, 8);
                    if (m == 0) atomicAdd(&red[rt * 16 + q * 4 + i], p);
                } else {
                    float s2 = sigm(sn);
                    sv[rt][i] = s2;
                    s_sig[(rt * 16 + q * 4 + i) * STR + c] = (bf16_t)s2;  // own elem: race-free in place
                }
            }
        }
        __syncthreads();
    }

    if (tid < ROWS) out[rb + tid] = red[tid] + WfB[0];
}

extern "C" void kernel_launch(void* const* d_in, const int* in_sizes, int n_in,
                              void* d_out, int out_size, void* d_ws, size_t ws_size,
                              hipStream_t stream) {
    const float* x   = (const float*)d_in[0];
    const float* SwW = (const float*)d_in[1];
    const float* Swb = (const float*)d_in[2];
    const float* Uz  = (const float*)d_in[3];
    const float* Wz  = (const float*)d_in[4];
    const float* Bz  = (const float*)d_in[5];
    const float* Ug  = (const float*)d_in[6];
    const float* Wg  = (const float*)d_in[7];
    const float* Bg  = (const float*)d_in[8];
    const float* Ur  = (const float*)d_in[9];
    const float* Wr  = (const float*)d_in[10];
    const float* Br  = (const float*)d_in[11];
    const float* Uh  = (const float*)d_in[12];
    const float* Wh  = (const float*)d_in[13];
    const float* Bh  = (const float*)d_in[14];
    const float* WfW = (const float*)d_in[15];
    const float* WfB = (const float*)d_in[16];
    bf16_t* ws = (bf16_t*)d_ws;
    float* out = (float*)d_out;

    if (ws_size < (size_t)WS_ELEMS * sizeof(bf16_t)) return;  // need ~500 KB scratch

    dgm_prep<<<(WS_ELEMS + 255) / 256, 256, 0, stream>>>(SwW, Uz, Wz, Ug, Wg, Ur, Wr, Uh, Wh, ws);
    dgm_main<<<NBLK, THREADS, 0, stream>>>(x, Swb, Bz, Bg, Br, Bh, WfW, WfB, ws, out);
}

// Round 5
// 367.919 us; speedup vs baseline: 1.5134x; 1.0377x over previous
//
#include <hip/hip_runtime.h>

typedef __bf16 bf16_t;
typedef __bf16 bf16x8 __attribute__((ext_vector_type(8)));
typedef float f32x4 __attribute__((ext_vector_type(4)));

#define NL 3
#define HD 128
#define ROWS 64
#define STR 136          // bf16 row stride for S/SR tiles (272 B -> 16B-aligned, ~2-way LDS aliasing = free)
#define THREADS 512
#define BATCH 262144
#define NBLK (BATCH / ROWS)

// ws (d_ws) layout in bf16 elements: weights pre-swizzled into MFMA B-fragment order
#define SW_OFF 0                 // [ct=8][lane=64][j=8]                       = 4096
#define U_OFF  4096              // [l=3][g=4][ct=8][lane=64][j=8]             = 49152
#define W_OFF  53248             // [l=3][g=4][ct=8][kc=4][lane=64][j=8]       = 196608
#define WS_ELEMS 249856          // total bf16 elems (499712 bytes)

#define MFMA(a, b, c) __builtin_amdgcn_mfma_f32_16x16x32_bf16((a), (b), (c), 0, 0, 0)

// 4-VALU activations: v_exp_f32 + v_rcp_f32 (1-ulp, saturating limits are exact)
#define LOG2E 1.4426950408889634f
__device__ __forceinline__ float sigm(float v) {
    return __builtin_amdgcn_rcpf(1.f + __builtin_amdgcn_exp2f(-LOG2E * v));
}
__device__ __forceinline__ float tanh_f(float v) {
    return 1.f - 2.f * __builtin_amdgcn_rcpf(__builtin_amdgcn_exp2f((2.f * LOG2E) * v) + 1.f);
}

// ---------------- prep: swizzle f32 weights into bf16 MFMA B-fragment order in ws ----------------
// B-frag layout for mfma_f32_16x16x32_bf16: lane holds B[k = (lane>>4)*8 + j][n = lane&15]
__global__ void dgm_prep(const float* __restrict__ SwW,
                         const float* __restrict__ Uz, const float* __restrict__ Wz,
                         const float* __restrict__ Ug, const float* __restrict__ Wg,
                         const float* __restrict__ Ur, const float* __restrict__ Wr,
                         const float* __restrict__ Uh, const float* __restrict__ Wh,
                         bf16_t* __restrict__ ws) {
    int idx = blockIdx.x * 256 + threadIdx.x;
    if (idx >= WS_ELEMS) return;
    const float* Us[4] = {Uz, Ug, Ur, Uh};
    const float* Wm[4] = {Wz, Wg, Wr, Wh};
    if (idx < U_OFF) {
        int ct = idx >> 9, rem = idx & 511, lane = rem >> 3, j = rem & 7;
        int q = lane >> 4, mm = lane & 15;
        int k = q * 8 + j, n = ct * 16 + mm;
        ws[idx] = (k < 8) ? (bf16_t)SwW[k * HD + n] : (bf16_t)0.f;
    } else if (idx < W_OFF) {
        int t = idx - U_OFF;
        int lg = t >> 12, r2 = t & 4095;
        int l = lg >> 2, g = lg & 3;
        int ct = r2 >> 9, rem = r2 & 511, lane = rem >> 3, j = rem & 7;
        int q = lane >> 4, mm = lane & 15;
        int k = q * 8 + j, n = ct * 16 + mm;
        ws[idx] = (k < 8) ? (bf16_t)Us[g][(l * 8 + k) * HD + n] : (bf16_t)0.f;
    } else {
        int t = idx - W_OFF;
        int lg = t >> 14, r2 = t & 16383;
        int l = lg >> 2, g = lg & 3;
        int ct = r2 >> 11, kc = (r2 >> 9) & 3, rem = r2 & 511, lane = rem >> 3, j = rem & 7;
        int q = lane >> 4, mm = lane & 15;
        int k = kc * 32 + q * 8 + j, n = ct * 16 + mm;
        ws[idx] = (bf16_t)Wm[g][(l * HD + k) * HD + n];
    }
}

// ---------------- main fused kernel: wave = one 16-col tile; R-phase / ZGH-phase split ----------------
__global__ __launch_bounds__(THREADS, 4) void dgm_main(
    const float* __restrict__ x,
    const float* __restrict__ Swb,
    const float* __restrict__ Bz, const float* __restrict__ Bg,
    const float* __restrict__ Br, const float* __restrict__ Bh,
    const float* __restrict__ WfW, const float* __restrict__ WfB,
    const bf16_t* __restrict__ ws,
    float* __restrict__ out) {
    __shared__ __align__(16) bf16_t s_sig[2][ROWS * STR];  // sigma(S) ping-pong across layers
    __shared__ __align__(16) bf16_t s_r[ROWS * STR];       // sigma(S)*R
    __shared__ float red[ROWS];                            // final-dot reduction

    const int tid = threadIdx.x;
    const int lane = tid & 63;
    const int ct = tid >> 6;           // wave owns column tile ct (cols ct*16..ct*16+15), all 64 rows
    const int m = lane & 15, q = lane >> 4;
    const int rb = blockIdx.x * ROWS;
    const int c = ct * 16 + m;         // this thread's fixed output column
    const int fragoff = (ct * 64 + lane) * 8;

    if (tid < ROWS) red[tid] = 0.f;

    // x A-fragments for the 4 row-tiles (lanes q==0 hold x[row][0..7]; quads 1..3 zero K-padding)
    bf16x8 xf[4];
#pragma unroll
    for (int rt = 0; rt < 4; rt++) {
#pragma unroll
        for (int i = 0; i < 8; i++) xf[rt][i] = (bf16_t)0.f;
        if (q == 0) {
            const float* xr = x + (size_t)(rb + rt * 16 + m) * 8;
#pragma unroll
            for (int i = 0; i < 8; i++) xf[rt][i] = (bf16_t)xr[i];
        }
    }

    // ---- init: S0 = x@Sw + b; sv = sigma(S0) in regs + LDS
    float sv[4][4];
    {
        const float swb = Swb[c];
        bf16x8 fSw = *(const bf16x8*)(ws + SW_OFF + fragoff);
#pragma unroll
        for (int rt = 0; rt < 4; rt++) {
            f32x4 acc = {0.f, 0.f, 0.f, 0.f};
            acc = MFMA(xf[rt], fSw, acc);
#pragma unroll
            for (int i = 0; i < 4; i++) {
                float s0 = sigm(acc[i] + swb);
                sv[rt][i] = s0;
                s_sig[0][(rt * 16 + q * 4 + i) * STR + c] = (bf16_t)s0;
            }
        }
    }
    __syncthreads();

#pragma unroll 1
    for (int l = 0; l < NL; l++) {
        const int cur = l & 1, nxt = cur ^ 1;
        const bf16_t* wb = ws + W_OFF + (size_t)l * 4 * 16384;
        const bf16_t* ub = ws + U_OFF + (size_t)l * 4 * 4096;

        // ---- P_A: R only (5 weight frags live = 20 VGPRs)
        {
            bf16x8 fUr = *(const bf16x8*)(ub + 2 * 4096 + fragoff);
            bf16x8 fWr[4];
#pragma unroll
            for (int kc = 0; kc < 4; kc++)
                fWr[kc] = *(const bf16x8*)(wb + 2 * 16384 + (ct * 4 + kc) * 512 + lane * 8);
            const float br = Br[l * HD + c];
#pragma unroll
            for (int rt = 0; rt < 4; rt++) {
                f32x4 aR = {0.f, 0.f, 0.f, 0.f};
                aR = MFMA(xf[rt], fUr, aR);
#pragma unroll
                for (int kc = 0; kc < 4; kc++) {
                    bf16x8 a = *(const bf16x8*)(&s_sig[cur][(rt * 16 + m) * STR + kc * 32 + q * 8]);
                    aR = MFMA(a, fWr[kc], aR);
                }
#pragma unroll
                for (int i = 0; i < 4; i++) {
                    float rv = sigm(aR[i] + br);
                    s_r[(rt * 16 + q * 4 + i) * STR + c] = (bf16_t)(rv * sv[rt][i]);
                }
            }
        }
        __syncthreads();

        // ---- P_B: Z, G, H together (15 weight frags = 60 VGPRs; 12 transient acc)
        {
            bf16x8 fUz = *(const bf16x8*)(ub + 0 * 4096 + fragoff);
            bf16x8 fUg = *(const bf16x8*)(ub + 1 * 4096 + fragoff);
            bf16x8 fUh = *(const bf16x8*)(ub + 3 * 4096 + fragoff);
            bf16x8 fWz[4], fWg[4], fWh[4];
#pragma unroll
            for (int kc = 0; kc < 4; kc++) {
                fWz[kc] = *(const bf16x8*)(wb + 0 * 16384 + (ct * 4 + kc) * 512 + lane * 8);
                fWg[kc] = *(const bf16x8*)(wb + 1 * 16384 + (ct * 4 + kc) * 512 + lane * 8);
                fWh[kc] = *(const bf16x8*)(wb + 3 * 16384 + (ct * 4 + kc) * 512 + lane * 8);
            }
            const float bz = Bz[l * HD + c], bg = Bg[l * HD + c], bh = Bh[l * HD + c];
            const bool last = (l == NL - 1);
            const float wfc = WfW[c];
#pragma unroll
            for (int rt = 0; rt < 4; rt++) {
                f32x4 aZ = {0.f, 0.f, 0.f, 0.f}, aG = {0.f, 0.f, 0.f, 0.f}, aH = {0.f, 0.f, 0.f, 0.f};
                aZ = MFMA(xf[rt], fUz, aZ);
                aG = MFMA(xf[rt], fUg, aG);
                aH = MFMA(xf[rt], fUh, aH);
#pragma unroll
                for (int kc = 0; kc < 4; kc++) {
                    bf16x8 as = *(const bf16x8*)(&s_sig[cur][(rt * 16 + m) * STR + kc * 32 + q * 8]);
                    bf16x8 ar = *(const bf16x8*)(&s_r[(rt * 16 + m) * STR + kc * 32 + q * 8]);
                    aZ = MFMA(as, fWz[kc], aZ);
                    aG = MFMA(as, fWg[kc], aG);
                    aH = MFMA(ar, fWh[kc], aH);
                }
#pragma unroll
                for (int i = 0; i < 4; i++) {
                    float z = sigm(aZ[i] + bz);
                    float g = sigm(aG[i] + bg);
                    float hh = tanh_f(aH[i] + bh);
                    float sn = (1.f - g) * hh + z * sv[rt][i];
                    if (last) {
                        float p = sn * wfc;           // S3 stays f32: fold S3@Wf into epilogue
                        p += __shfl_xor(p, 1);
                        p += __shfl_xor(p, 2);
                        p += __shfl_xor(p, 4);
                        p += __shfl_xor(p, 8);
                        if (m == 0) atomicAdd(&red[rt * 16 + q * 4 + i], p);
                    } else {
                        float s2 = sigm(sn);
                        sv[rt][i] = s2;
                        s_sig[nxt][(rt * 16 + q * 4 + i) * STR + c] = (bf16_t)s2;
                    }
                }
            }
        }
        __syncthreads();
    }

    if (tid < ROWS) out[rb + tid] = red[tid] + WfB[0];
}

extern "C" void kernel_launch(void* const* d_in, const int* in_sizes, int n_in,
                              void* d_out, int out_size, void* d_ws, size_t ws_size,
                              hipStream_t stream) {
    const float* x   = (const float*)d_in[0];
    const float* SwW = (const float*)d_in[1];
    const float* Swb = (const float*)d_in[2];
    const float* Uz  = (const float*)d_in[3];
    const float* Wz  = (const float*)d_in[4];
    const float* Bz  = (const float*)d_in[5];
    const float* Ug  = (const float*)d_in[6];
    const float* Wg  = (const float*)d_in[7];
    const float* Bg  = (const float*)d_in[8];
    const float* Ur  = (const float*)d_in[9];
    const float* Wr  = (const float*)d_in[10];
    const float* Br  = (const float*)d_in[11];
    const float* Uh  = (const float*)d_in[12];
    const float* Wh  = (const float*)d_in[13];
    const float* Bh  = (const float*)d_in[14];
    const float* WfW = (const float*)d_in[15];
    const float* WfB = (const float*)d_in[16];
    bf16_t* ws = (bf16_t*)d_ws;
    float* out = (float*)d_out;

    if (ws_size < (size_t)WS_ELEMS * sizeof(bf16_t)) return;  // need ~500 KB scratch

    dgm_prep<<<(WS_ELEMS + 255) / 256, 256, 0, stream>>>(SwW, Uz, Wz, Ug, Wg, Ur, Wr, Uh, Wh, ws);
    dgm_main<<<NBLK, THREADS, 0, stream>>>(x, Swb, Bz, Bg, Br, Bh, WfW, WfB, ws, out);
}